// Round 5
// baseline (2697.044 us; speedup 1.0000x reference)
//
#include <hip/hip_runtime.h>
#include <math.h>

#define NPTS 16384
#define NBATCH 8
#define CIN 128
#define COUT 256
#define NP 1024
#define NS 32

#define NCELL 512     // 8x8x8 Morton cells
#define FPS_T 512     // threads per FPS block (8 waves, 2/SIMD -> 256 VGPR budget)
#define FPS_PP 32     // points per thread

// ---------------- spatial sort preprocessing ----------------
__device__ __forceinline__ int cell_of(float x, float y, float z)
{
  int ix = (int)(x * 8.0f); ix = ix < 0 ? 0 : (ix > 7 ? 7 : ix);
  int iy = (int)(y * 8.0f); iy = iy < 0 ? 0 : (iy > 7 ? 7 : iy);
  int iz = (int)(z * 8.0f); iz = iz < 0 ? 0 : (iz > 7 ? 7 : iz);
  int m = 0;
#pragma unroll
  for (int b = 0; b < 3; ++b)
    m |= (((ix >> b) & 1) << (3 * b)) | (((iy >> b) & 1) << (3 * b + 1))
       | (((iz >> b) & 1) << (3 * b + 2));
  return m;
}

__global__ void zero_hist_kernel(int* __restrict__ hist)
{
  hist[blockIdx.x * NCELL + threadIdx.x] = 0;
}

__global__ void hist_kernel(const float* __restrict__ xyz, int* __restrict__ hist)
{
  const int i = blockIdx.x * 256 + threadIdx.x;
  const int b = i >> 14, n = i & (NPTS - 1);
  const float* p = xyz + ((size_t)b * NPTS + n) * 3;
  atomicAdd(&hist[b * NCELL + cell_of(p[0], p[1], p[2])], 1);
}

__global__ void scan_kernel(const int* __restrict__ hist, int* __restrict__ cursor)
{
  __shared__ int s[NCELL];
  const int b = blockIdx.x, t = threadIdx.x;
  const int h = hist[b * NCELL + t];
  s[t] = h;
  __syncthreads();
  for (int off = 1; off < NCELL; off <<= 1) {
    const int v = (t >= off) ? s[t - off] : 0;
    __syncthreads();
    s[t] += v;
    __syncthreads();
  }
  cursor[b * NCELL + t] = s[t] - h;   // exclusive
}

__global__ void scatter_kernel(const float* __restrict__ xyz, int* __restrict__ cursor,
                               float* __restrict__ sx, float* __restrict__ sy,
                               float* __restrict__ sz, int* __restrict__ si)
{
  const int i = blockIdx.x * 256 + threadIdx.x;
  const int b = i >> 14, n = i & (NPTS - 1);
  const float* p = xyz + ((size_t)b * NPTS + n) * 3;
  const float x = p[0], y = p[1], z = p[2];
  const int pos = atomicAdd(&cursor[b * NCELL + cell_of(x, y, z)], 1);
  const size_t o = (size_t)b * NPTS + pos;
  sx[o] = x; sy[o] = y; sz[o] = z; si[o] = n;
}

// ---------------- DPP helpers ----------------
template <int CTRL>
__device__ __forceinline__ void dpp_max64(unsigned& hi, unsigned& lo)
{
  const unsigned ohi = (unsigned)__builtin_amdgcn_update_dpp((int)hi, (int)hi, CTRL, 0xF, 0xF, false);
  const unsigned olo = (unsigned)__builtin_amdgcn_update_dpp((int)lo, (int)lo, CTRL, 0xF, 0xF, false);
  const bool t = (ohi > hi) || (ohi == hi && olo > lo);
  hi = t ? ohi : hi;
  lo = t ? olo : lo;
}
// row_shr:1/2/4/8 = 0x111/0x112/0x114/0x118, row_bcast15 = 0x142, row_bcast31 = 0x143

// ---------------- FPS ----------------
// 1 block/batch, 512 thr (8 waves, 2/SIMD). __launch_bounds__(512,2) raises the
// VGPR cap to 256 so the ~175-reg per-thread state (32 Morton-adjacent points
// + dist + packed pids) actually stays register-resident — rounds 1-4 all
// spilled to scratch (VGPR_Count 52-84 vs ~90-130 declared values), which was
// the real bottleneck. Exact bbox cull; packed-u64-key DPP argmax reduce.
__global__ __launch_bounds__(FPS_T, 2)
void fps_kernel(const float* __restrict__ xyz,
                const float* __restrict__ sx, const float* __restrict__ sy,
                const float* __restrict__ sz, const int* __restrict__ si,
                int* __restrict__ fps_idx)
{
#pragma clang fp contract(off)
  const int b = blockIdx.x;
  const int t = threadIdx.x;
  const int lane = t & 63, w = t >> 6;    // 8 waves
  const float* __restrict__ X = xyz + (size_t)b * NPTS * 3;
  const size_t sb = (size_t)b * NPTS + t * FPS_PP;

  float px[FPS_PP], py[FPS_PP], pz[FPS_PP], dist[FPS_PP];
  int pidp[FPS_PP / 2];                   // 2x14-bit pids packed per u32
#pragma unroll
  for (int i = 0; i < FPS_PP; ++i) {
    px[i] = sx[sb + i]; py[i] = sy[sb + i]; pz[i] = sz[sb + i];
    dist[i] = 1e10f;
  }
#pragma unroll
  for (int i = 0; i < FPS_PP / 2; ++i)
    pidp[i] = si[sb + 2 * i] | (si[sb + 2 * i + 1] << 16);
#pragma unroll
  for (int i = 0; i < FPS_PP; ++i)
    asm volatile("" : "+v"(px[i]), "+v"(py[i]), "+v"(pz[i]));
#pragma unroll
  for (int i = 0; i < FPS_PP / 2; ++i)
    asm volatile("" : "+v"(pidp[i]));

  float xmn = px[0], xmx = px[0], ymn = py[0], ymx = py[0], zmn = pz[0], zmx = pz[0];
#pragma unroll
  for (int i = 1; i < FPS_PP; ++i) {
    xmn = fminf(xmn, px[i]); xmx = fmaxf(xmx, px[i]);
    ymn = fminf(ymn, py[i]); ymx = fmaxf(ymx, py[i]);
    zmn = fminf(zmn, pz[i]); zmx = fmaxf(zmx, pz[i]);
  }

  __shared__ unsigned long long redk[2][8];

  float mt = 1e10f;   // cached max over dist[] (exact: skipped iters are no-ops)
  int   ai = 0;       // cached argmax ORIGINAL index
  int   cur = 0;
  float lx = X[0], ly = X[1], lz = X[2];

  for (int k = 0; k < NP; ++k) {
    if (t == 0) fps_idx[b * NP + k] = cur;

    // exact conservative skip: d_min(c,bbox)^2 > mt*(1+1e-5) => no dist changes
    const float ddx = fmaxf(fmaxf(xmn - lx, lx - xmx), 0.0f);
    const float ddy = fmaxf(fmaxf(ymn - ly, ly - ymx), 0.0f);
    const float ddz = fmaxf(fmaxf(zmn - lz, lz - zmx), 0.0f);
    const float db2 = ddx * ddx + ddy * ddy + ddz * ddz;
    if (db2 <= mt * 1.00001f) {
      float m = -1.0f; int a = 0;
#pragma unroll
      for (int i = 0; i < FPS_PP; ++i) {
        const float dx = px[i] - lx, dy = py[i] - ly, dz = pz[i] - lz;
        const float d = ((dx * dx) + (dy * dy)) + (dz * dz);  // exact ref op order
        const float nd = fminf(dist[i], d);
        dist[i] = nd;
        const int pi = (pidp[i >> 1] >> ((i & 1) * 16)) & 0xFFFF;
        const bool g = (nd > m) || (nd == m && pi < a);       // tie -> min orig idx
        m = g ? nd : m;
        a = g ? pi : a;
      }
      mt = m; ai = a;
    }

    // intra-wave 64-lane max on key=(distbits<<32 | 16383-pid), 6 DPP steps
    unsigned hi = __float_as_uint(mt), lo = (unsigned)(16383 - ai);
    dpp_max64<0x111>(hi, lo);
    dpp_max64<0x112>(hi, lo);
    dpp_max64<0x114>(hi, lo);
    dpp_max64<0x118>(hi, lo);
    dpp_max64<0x142>(hi, lo);
    dpp_max64<0x143>(hi, lo);   // lane 63 holds the wave max
    const int p = k & 1;
    if (lane == 63)
      redk[p][w] = ((unsigned long long)hi << 32) | lo;
    __syncthreads();

    // cross-wave: every wave redundantly combines the 8 slots
    const unsigned long long kj = redk[p][lane & 7];   // ds_read_b64
    const unsigned shi = (unsigned)(kj >> 32), slo = (unsigned)kj;
    // speculative winner-coord gather (overlaps the DPP combine below)
    const int pj = 16383 - (int)(slo & 0x3FFFu);
    const float gx = X[pj * 3 + 0];
    const float gy = X[pj * 3 + 1];
    const float gz = X[pj * 3 + 2];
    unsigned h2 = shi, l2 = slo;
    dpp_max64<0x111>(h2, l2);
    dpp_max64<0x112>(h2, l2);
    dpp_max64<0x114>(h2, l2);   // lane 7 of each row = max over all 8 slots
    const unsigned kmh = (unsigned)__builtin_amdgcn_readlane((int)h2, 7);
    const unsigned kml = (unsigned)__builtin_amdgcn_readlane((int)l2, 7);
    cur = 16383 - (int)(kml & 0x3FFFu);
    const unsigned long long tmsk = __ballot(shi == kmh && slo == kml) & 0xFFull;
    const int bwl = (int)__builtin_ctzll(tmsk);
    lx = __uint_as_float((unsigned)__builtin_amdgcn_readlane(__float_as_int(gx), bwl));
    ly = __uint_as_float((unsigned)__builtin_amdgcn_readlane(__float_as_int(gy), bwl));
    lz = __uint_as_float((unsigned)__builtin_amdgcn_readlane(__float_as_int(gz), bwl));
    // one barrier/iter: parity double-buffer makes overwrite-while-read impossible
  }
}

// ---------------- Ball query ----------------
__global__ __launch_bounds__(256)
void ballq_kernel(const float* __restrict__ xyz, const int* __restrict__ fps_idx,
                  int* __restrict__ ball_idx)
{
#pragma clang fp contract(off)
  const int gw = (int)((blockIdx.x * blockDim.x + threadIdx.x) >> 6);
  const int lane = threadIdx.x & 63;
  const int b = gw >> 10, s = gw & 1023;
  const float* __restrict__ X = xyz + (size_t)b * NPTS * 3;
  const int ci = fps_idx[b * NP + s];
  const float cx = X[ci * 3 + 0], cy = X[ci * 3 + 1], cz = X[ci * 3 + 2];
  const float n2 = ((cx * cx) + (cy * cy)) + (cz * cz);
  int* __restrict__ out = ball_idx + (size_t)(b * NP + s) * NS;

  int cnt = 0;
  int first = -1;
  for (int c0 = 0; c0 < NPTS && cnt < NS; c0 += 64) {
    const int p = c0 + lane;
    const float x = X[p * 3 + 0], y = X[p * 3 + 1], z = X[p * 3 + 2];
    const float x2 = ((x * x) + (y * y)) + (z * z);
    const float dt = ((cx * x) + (cy * y)) + (cz * z);
    const float d2 = (n2 + x2) - (2.0f * dt);
    const bool inball = d2 < 0.04f;
    const unsigned long long mm = __ballot(inball);
    if (inball) {
      const int pos = cnt + __popcll(mm & ((1ull << lane) - 1ull));
      if (pos < NS) out[pos] = p;
    }
    if (first < 0 && mm != 0ull) first = c0 + __builtin_ctzll(mm);
    cnt += __popcll(mm);
  }
  if (cnt < NS) {
    if (first < 0) first = 0;
    if (lane >= cnt && lane < NS) out[lane] = first;
  }
}

// ---------------- Transpose feats [B][C][N] -> [B][N][C] ----------------
__global__ __launch_bounds__(256)
void transpose_kernel(const float* __restrict__ feats, float* __restrict__ featsT)
{
  __shared__ float t[32][33];
  const int b = blockIdx.z;
  const int cb = blockIdx.y * 32;
  const int nb = blockIdx.x * 32;
  const int tx = threadIdx.x;
  const int ty = threadIdx.y;
  const float* __restrict__ F = feats + (size_t)b * CIN * NPTS;
#pragma unroll
  for (int i = 0; i < 32; i += 8)
    t[ty + i][tx] = F[(size_t)(cb + ty + i) * NPTS + nb + tx];
  __syncthreads();
  float* __restrict__ FT_ = featsT + (size_t)b * NPTS * CIN;
#pragma unroll
  for (int i = 0; i < 32; i += 8)
    FT_[(size_t)(nb + ty + i) * CIN + cb + tx] = t[tx][ty + i];
}

// ---------------- Gather + max-pool ----------------
__global__ __launch_bounds__(128)
void pool_kernel(const float* __restrict__ featsT, const int* __restrict__ ball_idx,
                 float* __restrict__ pooled)
{
  const int bs = blockIdx.x;
  const int c = threadIdx.x;
  const int b = bs >> 10;
  const int* __restrict__ idx = ball_idx + (size_t)bs * NS;
  const float* __restrict__ FT_ = featsT + (size_t)b * NPTS * CIN;
  float m = -INFINITY;
#pragma unroll 4
  for (int k = 0; k < NS; ++k) {
    const int n = idx[k];
    m = fmaxf(m, FT_[(size_t)n * CIN + c]);
  }
  pooled[(size_t)bs * CIN + c] = m;
}

// ---------------- 1x1 conv + BN + LeakyReLU ----------------
#define GO 128
#define GS 64
__global__ __launch_bounds__(256, 1)
void gemm_kernel(const float* __restrict__ pooled, const float* __restrict__ W,
                 const float* __restrict__ gamma, const float* __restrict__ beta,
                 const float* __restrict__ mean, const float* __restrict__ var,
                 float* __restrict__ out)
{
  __shared__ float Wt[128 * 132];
  __shared__ float Pl[128 * 68];
  const int b = blockIdx.z;
  const int ob = blockIdx.y * GO;
  const int sb = blockIdx.x * GS;
  const int tid = threadIdx.x;

  for (int i = tid; i < GO * 128; i += 256) {
    const int o = i >> 7, c = i & 127;
    Wt[c * 132 + o] = W[(ob + o) * 128 + c];
  }
  const float* __restrict__ P = pooled + (size_t)(b * NP + sb) * 128;
  for (int i = tid; i < GS * 128; i += 256) {
    const int s = i >> 7, c = i & 127;
    Pl[c * 68 + s] = P[s * 128 + c];
  }
  __syncthreads();

  const int to = tid & 31, ts = tid >> 5;
  const int o0 = to * 4, s0 = ts * 8;
  float acc[4][8];
#pragma unroll
  for (int o = 0; o < 4; ++o)
#pragma unroll
    for (int j = 0; j < 8; ++j) acc[o][j] = 0.0f;

  for (int c = 0; c < 128; ++c) {
    const float4 wv = *(const float4*)&Wt[c * 132 + o0];
    const float4 pa = *(const float4*)&Pl[c * 68 + s0];
    const float4 pb = *(const float4*)&Pl[c * 68 + s0 + 4];
    const float wr[4] = {wv.x, wv.y, wv.z, wv.w};
    const float pr[8] = {pa.x, pa.y, pa.z, pa.w, pb.x, pb.y, pb.z, pb.w};
#pragma unroll
    for (int o = 0; o < 4; ++o)
#pragma unroll
      for (int j = 0; j < 8; ++j)
        acc[o][j] = fmaf(wr[o], pr[j], acc[o][j]);
  }

#pragma unroll
  for (int o = 0; o < 4; ++o) {
    const int oo = ob + o0 + o;
    const float sc = gamma[oo] / sqrtf(var[oo] + 1e-5f);
    const float sh = beta[oo] - mean[oo] * sc;
    float r[8];
#pragma unroll
    for (int j = 0; j < 8; ++j) {
      const float y = fmaf(acc[o][j], sc, sh);
      r[j] = (y >= 0.0f) ? y : 0.2f * y;
    }
    float* __restrict__ O = out + (size_t)(b * COUT + oo) * NP + sb + s0;
    *(float4*)&O[0] = make_float4(r[0], r[1], r[2], r[3]);
    *(float4*)&O[4] = make_float4(r[4], r[5], r[6], r[7]);
  }
}

// ---------------- launch ----------------
extern "C" void kernel_launch(void* const* d_in, const int* in_sizes, int n_in,
                              void* d_out, int out_size, void* d_ws, size_t ws_size,
                              hipStream_t stream)
{
  (void)in_sizes; (void)n_in; (void)out_size; (void)ws_size;
  const float* xyz   = (const float*)d_in[0];
  const float* feats = (const float*)d_in[1];
  const float* W     = (const float*)d_in[2];
  const float* gamma = (const float*)d_in[3];
  const float* beta  = (const float*)d_in[4];
  const float* mean  = (const float*)d_in[5];
  const float* var   = (const float*)d_in[6];
  float* out = (float*)d_out;

  char* ws = (char*)d_ws;
  // fps_idx [32KB] @0 | ball_idx [1MB] @32768 | featsT [64MB] @1081344 |
  // pooled [4MB] @68190208. Sort scratch aliases featsT head (dead before
  // transpose runs; stream order guarantees no overlap-in-time).
  int*   fps_idx  = (int*)(ws + 0);
  int*   ball_idx = (int*)(ws + 32768);
  char*  fbase    = ws + 1081344;
  float* featsT   = (float*)fbase;
  float* pooled   = (float*)(ws + 68190208);

  float* sx     = (float*)(fbase + 0);
  float* sy     = (float*)(fbase + 524288);
  float* sz     = (float*)(fbase + 1048576);
  int*   si     = (int*)(fbase + 1572864);
  int*   hist   = (int*)(fbase + 2097152);
  int*   cursor = (int*)(fbase + 2113536);

  zero_hist_kernel<<<NBATCH, NCELL, 0, stream>>>(hist);
  hist_kernel<<<(NBATCH * NPTS) / 256, 256, 0, stream>>>(xyz, hist);
  scan_kernel<<<NBATCH, NCELL, 0, stream>>>(hist, cursor);
  scatter_kernel<<<(NBATCH * NPTS) / 256, 256, 0, stream>>>(xyz, cursor, sx, sy, sz, si);
  fps_kernel<<<NBATCH, FPS_T, 0, stream>>>(xyz, sx, sy, sz, si, fps_idx);
  ballq_kernel<<<(NBATCH * NP) / 4, 256, 0, stream>>>(xyz, fps_idx, ball_idx);
  transpose_kernel<<<dim3(NPTS / 32, CIN / 32, NBATCH), dim3(32, 8), 0, stream>>>(feats, featsT);
  pool_kernel<<<NBATCH * NP, CIN, 0, stream>>>(featsT, ball_idx, pooled);
  gemm_kernel<<<dim3(NP / GS, COUT / GO, NBATCH), 256, 0, stream>>>(pooled, W, gamma, beta, mean, var, out);
}

// Round 6
// 2680.624 us; speedup vs baseline: 1.0061x; 1.0061x over previous
//
#include <hip/hip_runtime.h>
#include <math.h>

#define NPTS 16384
#define NBATCH 8
#define CIN 128
#define COUT 256
#define NP 1024
#define NS 32

#define NCELL 512     // 8x8x8 Morton cells
#define FPS_T 512     // 8 waves = 2/EU
#define FPS_PP 32     // points per thread

// ---------------- spatial sort preprocessing ----------------
__device__ __forceinline__ int cell_of(float x, float y, float z)
{
  int ix = (int)(x * 8.0f); ix = ix < 0 ? 0 : (ix > 7 ? 7 : ix);
  int iy = (int)(y * 8.0f); iy = iy < 0 ? 0 : (iy > 7 ? 7 : iy);
  int iz = (int)(z * 8.0f); iz = iz < 0 ? 0 : (iz > 7 ? 7 : iz);
  int m = 0;
#pragma unroll
  for (int b = 0; b < 3; ++b)
    m |= (((ix >> b) & 1) << (3 * b)) | (((iy >> b) & 1) << (3 * b + 1))
       | (((iz >> b) & 1) << (3 * b + 2));
  return m;
}

__global__ void zero_hist_kernel(int* __restrict__ hist)
{
  hist[blockIdx.x * NCELL + threadIdx.x] = 0;
}

__global__ void hist_kernel(const float* __restrict__ xyz, int* __restrict__ hist)
{
  const int i = blockIdx.x * 256 + threadIdx.x;
  const int b = i >> 14, n = i & (NPTS - 1);
  const float* p = xyz + ((size_t)b * NPTS + n) * 3;
  atomicAdd(&hist[b * NCELL + cell_of(p[0], p[1], p[2])], 1);
}

__global__ void scan_kernel(const int* __restrict__ hist, int* __restrict__ cursor)
{
  __shared__ int s[NCELL];
  const int b = blockIdx.x, t = threadIdx.x;
  const int h = hist[b * NCELL + t];
  s[t] = h;
  __syncthreads();
  for (int off = 1; off < NCELL; off <<= 1) {
    const int v = (t >= off) ? s[t - off] : 0;
    __syncthreads();
    s[t] += v;
    __syncthreads();
  }
  cursor[b * NCELL + t] = s[t] - h;   // exclusive
}

__global__ void scatter_kernel(const float* __restrict__ xyz, int* __restrict__ cursor,
                               float* __restrict__ sx, float* __restrict__ sy,
                               float* __restrict__ sz, int* __restrict__ si)
{
  const int i = blockIdx.x * 256 + threadIdx.x;
  const int b = i >> 14, n = i & (NPTS - 1);
  const float* p = xyz + ((size_t)b * NPTS + n) * 3;
  const float x = p[0], y = p[1], z = p[2];
  const int pos = atomicAdd(&cursor[b * NCELL + cell_of(x, y, z)], 1);
  const size_t o = (size_t)b * NPTS + pos;
  sx[o] = x; sy[o] = y; sz[o] = z; si[o] = n;
}

// ---------------- DPP helpers ----------------
template <int CTRL>
__device__ __forceinline__ void dpp_max64(unsigned& hi, unsigned& lo)
{
  const unsigned ohi = (unsigned)__builtin_amdgcn_update_dpp((int)hi, (int)hi, CTRL, 0xF, 0xF, false);
  const unsigned olo = (unsigned)__builtin_amdgcn_update_dpp((int)lo, (int)lo, CTRL, 0xF, 0xF, false);
  const bool t = (ohi > hi) || (ohi == hi && olo > lo);
  hi = t ? ohi : hi;
  lo = t ? olo : lo;
}
// row_shr:1/2/4/8 = 0x111/0x112/0x114/0x118, row_bcast15 = 0x142, row_bcast31 = 0x143

// ---------------- FPS ----------------
// 1 block/batch, 512 thr (8 waves, 2/EU). amdgpu_waves_per_eu(2,2) pins
// occupancy at EXACTLY 2 waves/EU: with max==min the allocator has zero
// incentive to stay under 256 VGPRs, so the ~180-reg per-thread state (32
// Morton-adjacent pts: coords+dist+packed pids) can finally stay register-
// resident. Rounds 1-5 all spilled (VGPR 52-92 vs >=144 needed) because
// min-only bounds let the allocator chase higher occupancy and spill.
__global__ __launch_bounds__(FPS_T)
__attribute__((amdgpu_waves_per_eu(2, 2)))
void fps_kernel(const float* __restrict__ xyz,
                const float* __restrict__ sx, const float* __restrict__ sy,
                const float* __restrict__ sz, const int* __restrict__ si,
                int* __restrict__ fps_idx)
{
#pragma clang fp contract(off)
  const int b = blockIdx.x;
  const int t = threadIdx.x;
  const int lane = t & 63, w = t >> 6;    // 8 waves
  const float* __restrict__ X = xyz + (size_t)b * NPTS * 3;
  const size_t sb = (size_t)b * NPTS + t * FPS_PP;

  float px[FPS_PP], py[FPS_PP], pz[FPS_PP], dist[FPS_PP];
  int pidp[FPS_PP / 2];                   // 2x14-bit pids packed per u32
#pragma unroll
  for (int i = 0; i < FPS_PP; ++i) {
    px[i] = sx[sb + i]; py[i] = sy[sb + i]; pz[i] = sz[sb + i];
    dist[i] = 1e10f;
  }
#pragma unroll
  for (int i = 0; i < FPS_PP / 2; ++i)
    pidp[i] = si[sb + 2 * i] | (si[sb + 2 * i + 1] << 16);
#pragma unroll
  for (int i = 0; i < FPS_PP; ++i)
    asm volatile("" : "+v"(px[i]), "+v"(py[i]), "+v"(pz[i]));
#pragma unroll
  for (int i = 0; i < FPS_PP / 2; ++i)
    asm volatile("" : "+v"(pidp[i]));

  float xmn = px[0], xmx = px[0], ymn = py[0], ymx = py[0], zmn = pz[0], zmx = pz[0];
#pragma unroll
  for (int i = 1; i < FPS_PP; ++i) {
    xmn = fminf(xmn, px[i]); xmx = fmaxf(xmx, px[i]);
    ymn = fminf(ymn, py[i]); ymx = fmaxf(ymx, py[i]);
    zmn = fminf(zmn, pz[i]); zmx = fmaxf(zmx, pz[i]);
  }

  __shared__ unsigned long long redk[2][8];

  float mt = 1e10f;   // cached max over dist[] (exact: skipped iters are no-ops)
  int   ai = 0;       // cached argmax ORIGINAL index
  int   cur = 0;
  float lx = X[0], ly = X[1], lz = X[2];

  for (int k = 0; k < NP; ++k) {
    if (t == 0) fps_idx[b * NP + k] = cur;

    // exact conservative skip: d_min(c,bbox)^2 > mt*(1+1e-5) => no dist changes
    const float ddx = fmaxf(fmaxf(xmn - lx, lx - xmx), 0.0f);
    const float ddy = fmaxf(fmaxf(ymn - ly, ly - ymx), 0.0f);
    const float ddz = fmaxf(fmaxf(zmn - lz, lz - zmx), 0.0f);
    const float db2 = ddx * ddx + ddy * ddy + ddz * ddz;
    if (db2 <= mt * 1.00001f) {
      float m = -1.0f; int a = 0;
#pragma unroll
      for (int i = 0; i < FPS_PP; ++i) {
        const float dx = px[i] - lx, dy = py[i] - ly, dz = pz[i] - lz;
        const float d = ((dx * dx) + (dy * dy)) + (dz * dz);  // exact ref op order
        const float nd = fminf(dist[i], d);
        dist[i] = nd;
        const int pi = (pidp[i >> 1] >> ((i & 1) * 16)) & 0xFFFF;
        const bool g = (nd > m) || (nd == m && pi < a);       // tie -> min orig idx
        m = g ? nd : m;
        a = g ? pi : a;
      }
      mt = m; ai = a;
    }

    // intra-wave 64-lane max on key=(distbits<<32 | 16383-pid), 6 DPP steps
    unsigned hi = __float_as_uint(mt), lo = (unsigned)(16383 - ai);
    dpp_max64<0x111>(hi, lo);
    dpp_max64<0x112>(hi, lo);
    dpp_max64<0x114>(hi, lo);
    dpp_max64<0x118>(hi, lo);
    dpp_max64<0x142>(hi, lo);
    dpp_max64<0x143>(hi, lo);   // lane 63 holds the wave max
    const int p = k & 1;
    if (lane == 63)
      redk[p][w] = ((unsigned long long)hi << 32) | lo;
    __syncthreads();

    // cross-wave: every wave redundantly combines the 8 slots
    const unsigned long long kj = redk[p][lane & 7];   // ds_read_b64
    const unsigned shi = (unsigned)(kj >> 32), slo = (unsigned)kj;
    // speculative winner-coord gather (overlaps the DPP combine below)
    const int pj = 16383 - (int)(slo & 0x3FFFu);
    const float gx = X[pj * 3 + 0];
    const float gy = X[pj * 3 + 1];
    const float gz = X[pj * 3 + 2];
    unsigned h2 = shi, l2 = slo;
    dpp_max64<0x111>(h2, l2);
    dpp_max64<0x112>(h2, l2);
    dpp_max64<0x114>(h2, l2);   // lane 7 of each row = max over all 8 slots
    const unsigned kmh = (unsigned)__builtin_amdgcn_readlane((int)h2, 7);
    const unsigned kml = (unsigned)__builtin_amdgcn_readlane((int)l2, 7);
    cur = 16383 - (int)(kml & 0x3FFFu);
    const unsigned long long tmsk = __ballot(shi == kmh && slo == kml) & 0xFFull;
    const int bwl = (int)__builtin_ctzll(tmsk);
    lx = __uint_as_float((unsigned)__builtin_amdgcn_readlane(__float_as_int(gx), bwl));
    ly = __uint_as_float((unsigned)__builtin_amdgcn_readlane(__float_as_int(gy), bwl));
    lz = __uint_as_float((unsigned)__builtin_amdgcn_readlane(__float_as_int(gz), bwl));
    // one barrier/iter: parity double-buffer makes overwrite-while-read impossible
  }
}

// ---------------- Ball query ----------------
__global__ __launch_bounds__(256)
void ballq_kernel(const float* __restrict__ xyz, const int* __restrict__ fps_idx,
                  int* __restrict__ ball_idx)
{
#pragma clang fp contract(off)
  const int gw = (int)((blockIdx.x * blockDim.x + threadIdx.x) >> 6);
  const int lane = threadIdx.x & 63;
  const int b = gw >> 10, s = gw & 1023;
  const float* __restrict__ X = xyz + (size_t)b * NPTS * 3;
  const int ci = fps_idx[b * NP + s];
  const float cx = X[ci * 3 + 0], cy = X[ci * 3 + 1], cz = X[ci * 3 + 2];
  const float n2 = ((cx * cx) + (cy * cy)) + (cz * cz);
  int* __restrict__ out = ball_idx + (size_t)(b * NP + s) * NS;

  int cnt = 0;
  int first = -1;
  for (int c0 = 0; c0 < NPTS && cnt < NS; c0 += 64) {
    const int p = c0 + lane;
    const float x = X[p * 3 + 0], y = X[p * 3 + 1], z = X[p * 3 + 2];
    const float x2 = ((x * x) + (y * y)) + (z * z);
    const float dt = ((cx * x) + (cy * y)) + (cz * z);
    const float d2 = (n2 + x2) - (2.0f * dt);
    const bool inball = d2 < 0.04f;
    const unsigned long long mm = __ballot(inball);
    if (inball) {
      const int pos = cnt + __popcll(mm & ((1ull << lane) - 1ull));
      if (pos < NS) out[pos] = p;
    }
    if (first < 0 && mm != 0ull) first = c0 + __builtin_ctzll(mm);
    cnt += __popcll(mm);
  }
  if (cnt < NS) {
    if (first < 0) first = 0;
    if (lane >= cnt && lane < NS) out[lane] = first;
  }
}

// ---------------- Transpose feats [B][C][N] -> [B][N][C] ----------------
__global__ __launch_bounds__(256)
void transpose_kernel(const float* __restrict__ feats, float* __restrict__ featsT)
{
  __shared__ float t[32][33];
  const int b = blockIdx.z;
  const int cb = blockIdx.y * 32;
  const int nb = blockIdx.x * 32;
  const int tx = threadIdx.x;
  const int ty = threadIdx.y;
  const float* __restrict__ F = feats + (size_t)b * CIN * NPTS;
#pragma unroll
  for (int i = 0; i < 32; i += 8)
    t[ty + i][tx] = F[(size_t)(cb + ty + i) * NPTS + nb + tx];
  __syncthreads();
  float* __restrict__ FT_ = featsT + (size_t)b * NPTS * CIN;
#pragma unroll
  for (int i = 0; i < 32; i += 8)
    FT_[(size_t)(nb + ty + i) * CIN + cb + tx] = t[tx][ty + i];
}

// ---------------- Gather + max-pool ----------------
__global__ __launch_bounds__(128)
void pool_kernel(const float* __restrict__ featsT, const int* __restrict__ ball_idx,
                 float* __restrict__ pooled)
{
  const int bs = blockIdx.x;
  const int c = threadIdx.x;
  const int b = bs >> 10;
  const int* __restrict__ idx = ball_idx + (size_t)bs * NS;
  const float* __restrict__ FT_ = featsT + (size_t)b * NPTS * CIN;
  float m = -INFINITY;
#pragma unroll 4
  for (int k = 0; k < NS; ++k) {
    const int n = idx[k];
    m = fmaxf(m, FT_[(size_t)n * CIN + c]);
  }
  pooled[(size_t)bs * CIN + c] = m;
}

// ---------------- 1x1 conv + BN + LeakyReLU ----------------
#define GO 128
#define GS 64
__global__ __launch_bounds__(256, 1)
void gemm_kernel(const float* __restrict__ pooled, const float* __restrict__ W,
                 const float* __restrict__ gamma, const float* __restrict__ beta,
                 const float* __restrict__ mean, const float* __restrict__ var,
                 float* __restrict__ out)
{
  __shared__ float Wt[128 * 132];
  __shared__ float Pl[128 * 68];
  const int b = blockIdx.z;
  const int ob = blockIdx.y * GO;
  const int sb = blockIdx.x * GS;
  const int tid = threadIdx.x;

  for (int i = tid; i < GO * 128; i += 256) {
    const int o = i >> 7, c = i & 127;
    Wt[c * 132 + o] = W[(ob + o) * 128 + c];
  }
  const float* __restrict__ P = pooled + (size_t)(b * NP + sb) * 128;
  for (int i = tid; i < GS * 128; i += 256) {
    const int s = i >> 7, c = i & 127;
    Pl[c * 68 + s] = P[s * 128 + c];
  }
  __syncthreads();

  const int to = tid & 31, ts = tid >> 5;
  const int o0 = to * 4, s0 = ts * 8;
  float acc[4][8];
#pragma unroll
  for (int o = 0; o < 4; ++o)
#pragma unroll
    for (int j = 0; j < 8; ++j) acc[o][j] = 0.0f;

  for (int c = 0; c < 128; ++c) {
    const float4 wv = *(const float4*)&Wt[c * 132 + o0];
    const float4 pa = *(const float4*)&Pl[c * 68 + s0];
    const float4 pb = *(const float4*)&Pl[c * 68 + s0 + 4];
    const float wr[4] = {wv.x, wv.y, wv.z, wv.w};
    const float pr[8] = {pa.x, pa.y, pa.z, pa.w, pb.x, pb.y, pb.z, pb.w};
#pragma unroll
    for (int o = 0; o < 4; ++o)
#pragma unroll
      for (int j = 0; j < 8; ++j)
        acc[o][j] = fmaf(wr[o], pr[j], acc[o][j]);
  }

#pragma unroll
  for (int o = 0; o < 4; ++o) {
    const int oo = ob + o0 + o;
    const float sc = gamma[oo] / sqrtf(var[oo] + 1e-5f);
    const float sh = beta[oo] - mean[oo] * sc;
    float r[8];
#pragma unroll
    for (int j = 0; j < 8; ++j) {
      const float y = fmaf(acc[o][j], sc, sh);
      r[j] = (y >= 0.0f) ? y : 0.2f * y;
    }
    float* __restrict__ O = out + (size_t)(b * COUT + oo) * NP + sb + s0;
    *(float4*)&O[0] = make_float4(r[0], r[1], r[2], r[3]);
    *(float4*)&O[4] = make_float4(r[4], r[5], r[6], r[7]);
  }
}

// ---------------- launch ----------------
extern "C" void kernel_launch(void* const* d_in, const int* in_sizes, int n_in,
                              void* d_out, int out_size, void* d_ws, size_t ws_size,
                              hipStream_t stream)
{
  (void)in_sizes; (void)n_in; (void)out_size; (void)ws_size;
  const float* xyz   = (const float*)d_in[0];
  const float* feats = (const float*)d_in[1];
  const float* W     = (const float*)d_in[2];
  const float* gamma = (const float*)d_in[3];
  const float* beta  = (const float*)d_in[4];
  const float* mean  = (const float*)d_in[5];
  const float* var   = (const float*)d_in[6];
  float* out = (float*)d_out;

  char* ws = (char*)d_ws;
  // fps_idx [32KB] @0 | ball_idx [1MB] @32768 | featsT [64MB] @1081344 |
  // pooled [4MB] @68190208. Sort scratch aliases featsT head (dead before
  // transpose runs; stream order guarantees no overlap-in-time).
  int*   fps_idx  = (int*)(ws + 0);
  int*   ball_idx = (int*)(ws + 32768);
  char*  fbase    = ws + 1081344;
  float* featsT   = (float*)fbase;
  float* pooled   = (float*)(ws + 68190208);

  float* sx     = (float*)(fbase + 0);
  float* sy     = (float*)(fbase + 524288);
  float* sz     = (float*)(fbase + 1048576);
  int*   si     = (int*)(fbase + 1572864);
  int*   hist   = (int*)(fbase + 2097152);
  int*   cursor = (int*)(fbase + 2113536);

  zero_hist_kernel<<<NBATCH, NCELL, 0, stream>>>(hist);
  hist_kernel<<<(NBATCH * NPTS) / 256, 256, 0, stream>>>(xyz, hist);
  scan_kernel<<<NBATCH, NCELL, 0, stream>>>(hist, cursor);
  scatter_kernel<<<(NBATCH * NPTS) / 256, 256, 0, stream>>>(xyz, cursor, sx, sy, sz, si);
  fps_kernel<<<NBATCH, FPS_T, 0, stream>>>(xyz, sx, sy, sz, si, fps_idx);
  ballq_kernel<<<(NBATCH * NP) / 4, 256, 0, stream>>>(xyz, fps_idx, ball_idx);
  transpose_kernel<<<dim3(NPTS / 32, CIN / 32, NBATCH), dim3(32, 8), 0, stream>>>(feats, featsT);
  pool_kernel<<<NBATCH * NP, CIN, 0, stream>>>(featsT, ball_idx, pooled);
  gemm_kernel<<<dim3(NP / GS, COUT / GO, NBATCH), 256, 0, stream>>>(pooled, W, gamma, beta, mean, var, out);
}

// Round 7
// 2132.635 us; speedup vs baseline: 1.2647x; 1.2570x over previous
//
#include <hip/hip_runtime.h>
#include <math.h>

#define NPTS 16384
#define NBATCH 8
#define CIN 128
#define COUT 256
#define NP 1024
#define NS 32

#define NCELL 512     // 8x8x8 Morton cells
#define FPS_T 1024    // 16 waves, 4/EU
#define FPS_PP 16     // points per thread

// ---------------- spatial sort preprocessing ----------------
__device__ __forceinline__ int cell_of(float x, float y, float z)
{
  int ix = (int)(x * 8.0f); ix = ix < 0 ? 0 : (ix > 7 ? 7 : ix);
  int iy = (int)(y * 8.0f); iy = iy < 0 ? 0 : (iy > 7 ? 7 : iy);
  int iz = (int)(z * 8.0f); iz = iz < 0 ? 0 : (iz > 7 ? 7 : iz);
  int m = 0;
#pragma unroll
  for (int b = 0; b < 3; ++b)
    m |= (((ix >> b) & 1) << (3 * b)) | (((iy >> b) & 1) << (3 * b + 1))
       | (((iz >> b) & 1) << (3 * b + 2));
  return m;
}

__global__ void zero_hist_kernel(int* __restrict__ hist)
{
  hist[blockIdx.x * NCELL + threadIdx.x] = 0;
}

__global__ void hist_kernel(const float* __restrict__ xyz, int* __restrict__ hist)
{
  const int i = blockIdx.x * 256 + threadIdx.x;
  const int b = i >> 14, n = i & (NPTS - 1);
  const float* p = xyz + ((size_t)b * NPTS + n) * 3;
  atomicAdd(&hist[b * NCELL + cell_of(p[0], p[1], p[2])], 1);
}

__global__ void scan_kernel(const int* __restrict__ hist, int* __restrict__ cursor)
{
  __shared__ int s[NCELL];
  const int b = blockIdx.x, t = threadIdx.x;
  const int h = hist[b * NCELL + t];
  s[t] = h;
  __syncthreads();
  for (int off = 1; off < NCELL; off <<= 1) {
    const int v = (t >= off) ? s[t - off] : 0;
    __syncthreads();
    s[t] += v;
    __syncthreads();
  }
  cursor[b * NCELL + t] = s[t] - h;   // exclusive
}

// Writes sorted points in TRANSPOSED-CHUNK layout: sorted position p lives at
// index (p%16)*1024 + p/16, so FPS thread t's i-th point (p = t*16+i) sits at
// [i*1024 + t] -> all staging loads / LDS reads / fallback refetches coalesce.
__global__ void scatter_kernel(const float* __restrict__ xyz, int* __restrict__ cursor,
                               float2* __restrict__ sxy2T, float* __restrict__ szT,
                               int* __restrict__ siT)
{
  const int i = blockIdx.x * 256 + threadIdx.x;
  const int b = i >> 14, n = i & (NPTS - 1);
  const float* p = xyz + ((size_t)b * NPTS + n) * 3;
  const float x = p[0], y = p[1], z = p[2];
  const int pos = atomicAdd(&cursor[b * NCELL + cell_of(x, y, z)], 1);
  const int q = (pos & (FPS_PP - 1)) * FPS_T + (pos >> 4);
  const size_t o = (size_t)b * NPTS + q;
  sxy2T[o] = make_float2(x, y);
  szT[o] = z;
  siT[o] = n;
}

// ---------------- DPP helpers ----------------
template <int CTRL>
__device__ __forceinline__ void dpp_max64(unsigned& hi, unsigned& lo)
{
  const unsigned ohi = (unsigned)__builtin_amdgcn_update_dpp((int)hi, (int)hi, CTRL, 0xF, 0xF, false);
  const unsigned olo = (unsigned)__builtin_amdgcn_update_dpp((int)lo, (int)lo, CTRL, 0xF, 0xF, false);
  const bool t = (ohi > hi) || (ohi == hi && olo > lo);
  hi = t ? ohi : hi;
  lo = t ? olo : lo;
}
// row_shr:1/2/4/8 = 0x111/0x112/0x114/0x118, row_bcast15 = 0x142, row_bcast31 = 0x143

// ---------------- FPS ----------------
// 1 block/batch, 1024 thr (16 waves, 4/EU). Coords (x,y) live in 128 KB LDS
// ([i][t] layout -> conflict-free ds_read_b64); z/pids in regs with a
// COALESCED global fallback (szT/siT) if the allocator remats them. This
// removes the rounds-1..6 pathology where the compiler re-fetched stride-16
// coords from L2 every iteration (VGPR 52-92 << array size; attributes
// couldn't force residency). dist[] (loop-carried) fits in regs. Exact bbox
// cull; packed-u64-key DPP argmax reduce; 1 barrier/iter.
__global__ __launch_bounds__(FPS_T)
void fps_kernel(const float* __restrict__ xyz,
                const float2* __restrict__ sxy2T, const float* __restrict__ szT,
                const int* __restrict__ siT, int* __restrict__ fps_idx)
{
#pragma clang fp contract(off)
  __shared__ float2 XY[FPS_PP * FPS_T];           // 128 KB
  __shared__ unsigned long long redk[2][16];
  const int b = blockIdx.x;
  const int t = threadIdx.x;
  const int lane = t & 63, w = t >> 6;            // 16 waves
  const float* __restrict__ X = xyz + (size_t)b * NPTS * 3;
  const size_t B0 = (size_t)b * NPTS;

  float z[FPS_PP], dist[FPS_PP];
  int pidp[FPS_PP / 2];
  float xmn = 1e30f, xmx = -1e30f, ymn = 1e30f, ymx = -1e30f, zmn = 1e30f, zmx = -1e30f;
#pragma unroll
  for (int i = 0; i < FPS_PP; ++i) {
    const float2 v = sxy2T[B0 + i * FPS_T + t];   // coalesced
    XY[i * FPS_T + t] = v;                        // conflict-free ds_write_b64
    z[i] = szT[B0 + i * FPS_T + t];               // coalesced
    dist[i] = 1e10f;
    xmn = fminf(xmn, v.x); xmx = fmaxf(xmx, v.x);
    ymn = fminf(ymn, v.y); ymx = fmaxf(ymx, v.y);
    zmn = fminf(zmn, z[i]); zmx = fmaxf(zmx, z[i]);
  }
#pragma unroll
  for (int i = 0; i < FPS_PP / 2; ++i)
    pidp[i] = siT[B0 + (2 * i) * FPS_T + t] | (siT[B0 + (2 * i + 1) * FPS_T + t] << 16);
  __syncthreads();

  float mt = 1e10f;   // cached max over dist[] (exact: skipped iters are no-ops)
  int   ai = 0;       // cached argmax ORIGINAL index
  int   cur = 0;
  float lx = X[0], ly = X[1], lz = X[2];

  for (int k = 0; k < NP; ++k) {
    if (t == 0) fps_idx[b * NP + k] = cur;

    // exact conservative skip: d_min(c,bbox)^2 > mt*(1+1e-5) => no dist changes
    const float ddx = fmaxf(fmaxf(xmn - lx, lx - xmx), 0.0f);
    const float ddy = fmaxf(fmaxf(ymn - ly, ly - ymx), 0.0f);
    const float ddz = fmaxf(fmaxf(zmn - lz, lz - zmx), 0.0f);
    const float db2 = ddx * ddx + ddy * ddy + ddz * ddz;
    if (db2 <= mt * 1.00001f) {
      float m = -1.0f; int a = 0;
#pragma unroll
      for (int i = 0; i < FPS_PP; ++i) {
        const float2 v = XY[i * FPS_T + t];       // ds_read_b64, conflict-free
        const float dx = v.x - lx, dy = v.y - ly, dz = z[i] - lz;
        const float d = ((dx * dx) + (dy * dy)) + (dz * dz);  // exact ref op order
        const float nd = fminf(dist[i], d);
        dist[i] = nd;
        const int pi = (pidp[i >> 1] >> ((i & 1) * 16)) & 0xFFFF;
        const bool g = (nd > m) || (nd == m && pi < a);       // tie -> min orig idx
        m = g ? nd : m;
        a = g ? pi : a;
      }
      mt = m; ai = a;
    }

    // intra-wave 64-lane max on key=(distbits<<32 | 16383-pid), 6 DPP steps
    unsigned hi = __float_as_uint(mt), lo = (unsigned)(16383 - ai);
    dpp_max64<0x111>(hi, lo);
    dpp_max64<0x112>(hi, lo);
    dpp_max64<0x114>(hi, lo);
    dpp_max64<0x118>(hi, lo);
    dpp_max64<0x142>(hi, lo);
    dpp_max64<0x143>(hi, lo);   // lane 63 holds the wave max
    const int p = k & 1;
    if (lane == 63)
      redk[p][w] = ((unsigned long long)hi << 32) | lo;
    __syncthreads();

    // cross-wave: every wave redundantly combines the 16 slots
    const unsigned long long kj = redk[p][lane & 15];   // ds_read_b64
    const unsigned shi = (unsigned)(kj >> 32), slo = (unsigned)kj;
    // speculative winner-coord gather (overlaps the DPP combine below)
    const int pj = 16383 - (int)(slo & 0x3FFFu);
    const float gx = X[pj * 3 + 0];
    const float gy = X[pj * 3 + 1];
    const float gz = X[pj * 3 + 2];
    unsigned h2 = shi, l2 = slo;
    dpp_max64<0x111>(h2, l2);
    dpp_max64<0x112>(h2, l2);
    dpp_max64<0x114>(h2, l2);
    dpp_max64<0x118>(h2, l2);   // lane 15 of each row = max over all 16 slots
    const unsigned kmh = (unsigned)__builtin_amdgcn_readlane((int)h2, 15);
    const unsigned kml = (unsigned)__builtin_amdgcn_readlane((int)l2, 15);
    cur = 16383 - (int)(kml & 0x3FFFu);
    const unsigned long long tmsk = __ballot(shi == kmh && slo == kml) & 0xFFFFull;
    const int bwl = (int)__builtin_ctzll(tmsk);
    lx = __uint_as_float((unsigned)__builtin_amdgcn_readlane(__float_as_int(gx), bwl));
    ly = __uint_as_float((unsigned)__builtin_amdgcn_readlane(__float_as_int(gy), bwl));
    lz = __uint_as_float((unsigned)__builtin_amdgcn_readlane(__float_as_int(gz), bwl));
    // one barrier/iter: parity double-buffer makes overwrite-while-read impossible
  }
}

// ---------------- Ball query ----------------
__global__ __launch_bounds__(256)
void ballq_kernel(const float* __restrict__ xyz, const int* __restrict__ fps_idx,
                  int* __restrict__ ball_idx)
{
#pragma clang fp contract(off)
  const int gw = (int)((blockIdx.x * blockDim.x + threadIdx.x) >> 6);
  const int lane = threadIdx.x & 63;
  const int b = gw >> 10, s = gw & 1023;
  const float* __restrict__ X = xyz + (size_t)b * NPTS * 3;
  const int ci = fps_idx[b * NP + s];
  const float cx = X[ci * 3 + 0], cy = X[ci * 3 + 1], cz = X[ci * 3 + 2];
  const float n2 = ((cx * cx) + (cy * cy)) + (cz * cz);
  int* __restrict__ out = ball_idx + (size_t)(b * NP + s) * NS;

  int cnt = 0;
  int first = -1;
  for (int c0 = 0; c0 < NPTS && cnt < NS; c0 += 64) {
    const int p = c0 + lane;
    const float x = X[p * 3 + 0], y = X[p * 3 + 1], z = X[p * 3 + 2];
    const float x2 = ((x * x) + (y * y)) + (z * z);
    const float dt = ((cx * x) + (cy * y)) + (cz * z);
    const float d2 = (n2 + x2) - (2.0f * dt);
    const bool inball = d2 < 0.04f;
    const unsigned long long mm = __ballot(inball);
    if (inball) {
      const int pos = cnt + __popcll(mm & ((1ull << lane) - 1ull));
      if (pos < NS) out[pos] = p;
    }
    if (first < 0 && mm != 0ull) first = c0 + __builtin_ctzll(mm);
    cnt += __popcll(mm);
  }
  if (cnt < NS) {
    if (first < 0) first = 0;
    if (lane >= cnt && lane < NS) out[lane] = first;
  }
}

// ---------------- Transpose feats [B][C][N] -> [B][N][C] ----------------
__global__ __launch_bounds__(256)
void transpose_kernel(const float* __restrict__ feats, float* __restrict__ featsT)
{
  __shared__ float t[32][33];
  const int b = blockIdx.z;
  const int cb = blockIdx.y * 32;
  const int nb = blockIdx.x * 32;
  const int tx = threadIdx.x;
  const int ty = threadIdx.y;
  const float* __restrict__ F = feats + (size_t)b * CIN * NPTS;
#pragma unroll
  for (int i = 0; i < 32; i += 8)
    t[ty + i][tx] = F[(size_t)(cb + ty + i) * NPTS + nb + tx];
  __syncthreads();
  float* __restrict__ FT_ = featsT + (size_t)b * NPTS * CIN;
#pragma unroll
  for (int i = 0; i < 32; i += 8)
    FT_[(size_t)(nb + ty + i) * CIN + cb + tx] = t[tx][ty + i];
}

// ---------------- Gather + max-pool ----------------
__global__ __launch_bounds__(128)
void pool_kernel(const float* __restrict__ featsT, const int* __restrict__ ball_idx,
                 float* __restrict__ pooled)
{
  const int bs = blockIdx.x;
  const int c = threadIdx.x;
  const int b = bs >> 10;
  const int* __restrict__ idx = ball_idx + (size_t)bs * NS;
  const float* __restrict__ FT_ = featsT + (size_t)b * NPTS * CIN;
  float m = -INFINITY;
#pragma unroll 4
  for (int k = 0; k < NS; ++k) {
    const int n = idx[k];
    m = fmaxf(m, FT_[(size_t)n * CIN + c]);
  }
  pooled[(size_t)bs * CIN + c] = m;
}

// ---------------- 1x1 conv + BN + LeakyReLU ----------------
#define GO 128
#define GS 64
__global__ __launch_bounds__(256, 1)
void gemm_kernel(const float* __restrict__ pooled, const float* __restrict__ W,
                 const float* __restrict__ gamma, const float* __restrict__ beta,
                 const float* __restrict__ mean, const float* __restrict__ var,
                 float* __restrict__ out)
{
  __shared__ float Wt[128 * 132];
  __shared__ float Pl[128 * 68];
  const int b = blockIdx.z;
  const int ob = blockIdx.y * GO;
  const int sb = blockIdx.x * GS;
  const int tid = threadIdx.x;

  for (int i = tid; i < GO * 128; i += 256) {
    const int o = i >> 7, c = i & 127;
    Wt[c * 132 + o] = W[(ob + o) * 128 + c];
  }
  const float* __restrict__ P = pooled + (size_t)(b * NP + sb) * 128;
  for (int i = tid; i < GS * 128; i += 256) {
    const int s = i >> 7, c = i & 127;
    Pl[c * 68 + s] = P[s * 128 + c];
  }
  __syncthreads();

  const int to = tid & 31, ts = tid >> 5;
  const int o0 = to * 4, s0 = ts * 8;
  float acc[4][8];
#pragma unroll
  for (int o = 0; o < 4; ++o)
#pragma unroll
    for (int j = 0; j < 8; ++j) acc[o][j] = 0.0f;

  for (int c = 0; c < 128; ++c) {
    const float4 wv = *(const float4*)&Wt[c * 132 + o0];
    const float4 pa = *(const float4*)&Pl[c * 68 + s0];
    const float4 pb = *(const float4*)&Pl[c * 68 + s0 + 4];
    const float wr[4] = {wv.x, wv.y, wv.z, wv.w};
    const float pr[8] = {pa.x, pa.y, pa.z, pa.w, pb.x, pb.y, pb.z, pb.w};
#pragma unroll
    for (int o = 0; o < 4; ++o)
#pragma unroll
      for (int j = 0; j < 8; ++j)
        acc[o][j] = fmaf(wr[o], pr[j], acc[o][j]);
  }

#pragma unroll
  for (int o = 0; o < 4; ++o) {
    const int oo = ob + o0 + o;
    const float sc = gamma[oo] / sqrtf(var[oo] + 1e-5f);
    const float sh = beta[oo] - mean[oo] * sc;
    float r[8];
#pragma unroll
    for (int j = 0; j < 8; ++j) {
      const float y = fmaf(acc[o][j], sc, sh);
      r[j] = (y >= 0.0f) ? y : 0.2f * y;
    }
    float* __restrict__ O = out + (size_t)(b * COUT + oo) * NP + sb + s0;
    *(float4*)&O[0] = make_float4(r[0], r[1], r[2], r[3]);
    *(float4*)&O[4] = make_float4(r[4], r[5], r[6], r[7]);
  }
}

// ---------------- launch ----------------
extern "C" void kernel_launch(void* const* d_in, const int* in_sizes, int n_in,
                              void* d_out, int out_size, void* d_ws, size_t ws_size,
                              hipStream_t stream)
{
  (void)in_sizes; (void)n_in; (void)out_size; (void)ws_size;
  const float* xyz   = (const float*)d_in[0];
  const float* feats = (const float*)d_in[1];
  const float* W     = (const float*)d_in[2];
  const float* gamma = (const float*)d_in[3];
  const float* beta  = (const float*)d_in[4];
  const float* mean  = (const float*)d_in[5];
  const float* var   = (const float*)d_in[6];
  float* out = (float*)d_out;

  char* ws = (char*)d_ws;
  // fps_idx [32KB] @0 | ball_idx [1MB] @32768 | featsT [64MB] @1081344 |
  // pooled [4MB] @68190208. Sort scratch aliases featsT head (dead before
  // transpose runs; stream order guarantees no overlap-in-time).
  int*   fps_idx  = (int*)(ws + 0);
  int*   ball_idx = (int*)(ws + 32768);
  char*  fbase    = ws + 1081344;
  float* featsT   = (float*)fbase;
  float* pooled   = (float*)(ws + 68190208);

  float2* sxy2T  = (float2*)(fbase + 0);        // 8*16384*8  = 1 MB
  float*  szT    = (float*)(fbase + 1048576);   // 8*16384*4  = 512 KB
  int*    siT    = (int*)(fbase + 1572864);     // 8*16384*4  = 512 KB
  int*    hist   = (int*)(fbase + 2097152);
  int*    cursor = (int*)(fbase + 2113536);

  zero_hist_kernel<<<NBATCH, NCELL, 0, stream>>>(hist);
  hist_kernel<<<(NBATCH * NPTS) / 256, 256, 0, stream>>>(xyz, hist);
  scan_kernel<<<NBATCH, NCELL, 0, stream>>>(hist, cursor);
  scatter_kernel<<<(NBATCH * NPTS) / 256, 256, 0, stream>>>(xyz, cursor, sxy2T, szT, siT);
  fps_kernel<<<NBATCH, FPS_T, 0, stream>>>(xyz, sxy2T, szT, siT, fps_idx);
  ballq_kernel<<<(NBATCH * NP) / 4, 256, 0, stream>>>(xyz, fps_idx, ball_idx);
  transpose_kernel<<<dim3(NPTS / 32, CIN / 32, NBATCH), dim3(32, 8), 0, stream>>>(feats, featsT);
  pool_kernel<<<NBATCH * NP, CIN, 0, stream>>>(featsT, ball_idx, pooled);
  gemm_kernel<<<dim3(NP / GS, COUT / GO, NBATCH), 256, 0, stream>>>(pooled, W, gamma, beta, mean, var, out);
}

// Round 8
// 1638.680 us; speedup vs baseline: 1.6459x; 1.3014x over previous
//
#include <hip/hip_runtime.h>
#include <math.h>

#define NPTS 16384
#define NBATCH 8
#define CIN 128
#define COUT 256
#define NP 1024
#define NS 32

#define NCELL 512     // 8x8x8 Morton cells
#define FPS_T 1024    // 16 waves, 4/EU
#define FPS_PP 16     // points per thread

// ---------------- spatial sort preprocessing ----------------
__device__ __forceinline__ int cell_of(float x, float y, float z)
{
  int ix = (int)(x * 8.0f); ix = ix < 0 ? 0 : (ix > 7 ? 7 : ix);
  int iy = (int)(y * 8.0f); iy = iy < 0 ? 0 : (iy > 7 ? 7 : iy);
  int iz = (int)(z * 8.0f); iz = iz < 0 ? 0 : (iz > 7 ? 7 : iz);
  int m = 0;
#pragma unroll
  for (int b = 0; b < 3; ++b)
    m |= (((ix >> b) & 1) << (3 * b)) | (((iy >> b) & 1) << (3 * b + 1))
       | (((iz >> b) & 1) << (3 * b + 2));
  return m;
}

__global__ void zero_hist_kernel(int* __restrict__ hist)
{
  hist[blockIdx.x * NCELL + threadIdx.x] = 0;
}

__global__ void hist_kernel(const float* __restrict__ xyz, int* __restrict__ hist)
{
  const int i = blockIdx.x * 256 + threadIdx.x;
  const int b = i >> 14, n = i & (NPTS - 1);
  const float* p = xyz + ((size_t)b * NPTS + n) * 3;
  atomicAdd(&hist[b * NCELL + cell_of(p[0], p[1], p[2])], 1);
}

__global__ void scan_kernel(const int* __restrict__ hist, int* __restrict__ cursor)
{
  __shared__ int s[NCELL];
  const int b = blockIdx.x, t = threadIdx.x;
  const int h = hist[b * NCELL + t];
  s[t] = h;
  __syncthreads();
  for (int off = 1; off < NCELL; off <<= 1) {
    const int v = (t >= off) ? s[t - off] : 0;
    __syncthreads();
    s[t] += v;
    __syncthreads();
  }
  cursor[b * NCELL + t] = s[t] - h;   // exclusive
}

// Transposed-chunk layout: sorted pos p -> slot (p%16)*1024 + p/16 so FPS
// thread t's i-th point (p=t*16+i) is at [i*1024+t] (coalesced). szS is the
// compact by-sorted-pos z array used for the winner-z gather.
__global__ void scatter_kernel(const float* __restrict__ xyz, int* __restrict__ cursor,
                               float2* __restrict__ sxy2T, float* __restrict__ szT,
                               float* __restrict__ szS, int* __restrict__ siT)
{
  const int i = blockIdx.x * 256 + threadIdx.x;
  const int b = i >> 14, n = i & (NPTS - 1);
  const float* p = xyz + ((size_t)b * NPTS + n) * 3;
  const float x = p[0], y = p[1], z = p[2];
  const int pos = atomicAdd(&cursor[b * NCELL + cell_of(x, y, z)], 1);
  const int q = (pos & (FPS_PP - 1)) * FPS_T + (pos >> 4);
  const size_t o = (size_t)b * NPTS + q;
  sxy2T[o] = make_float2(x, y);
  szT[o] = z;
  siT[o] = n;
  szS[(size_t)b * NPTS + pos] = z;
}

// ---------------- DPP helpers ----------------
template <int CTRL>
__device__ __forceinline__ void dpp_max64(unsigned& hi, unsigned& lo)
{
  const unsigned ohi = (unsigned)__builtin_amdgcn_update_dpp((int)hi, (int)hi, CTRL, 0xF, 0xF, false);
  const unsigned olo = (unsigned)__builtin_amdgcn_update_dpp((int)lo, (int)lo, CTRL, 0xF, 0xF, false);
  const bool t = (ohi > hi) || (ohi == hi && olo > lo);
  hi = t ? ohi : hi;
  lo = t ? olo : lo;
}
// row_shr:1/2/4/8 = 0x111/0x112/0x114/0x118, row_bcast15 = 0x142, row_bcast31 = 0x143

// ---------------- FPS ----------------
// 1 block/batch, 1024 thr (16 waves, 4/EU). (x,y) in 128KB LDS; z/pids in regs.
// WAVE-UNIFORM cull: per-wave bbox + cached wave key (its own max dist) ->
// s_cbranch skips update AND the 6-step DPP for far waves (exec-masked
// per-thread culling saved nothing: masked lanes still issue). Key packs
// (distbits<<32 | invpid<<14 | spos): tie-break = min original idx (exact),
// and spos lets the winner (x,y) come from LDS + z from compact szS --
// speculative 16-lane loads issued before the combine shrink the serial tail.
__global__ __launch_bounds__(FPS_T)
void fps_kernel(const float* __restrict__ xyz,
                const float2* __restrict__ sxy2T, const float* __restrict__ szT,
                const float* __restrict__ szS, const int* __restrict__ siT,
                int* __restrict__ fps_idx)
{
#pragma clang fp contract(off)
  __shared__ float2 XY[FPS_PP * FPS_T];           // 128 KB
  __shared__ unsigned long long redk[2][16];
  const int b = blockIdx.x;
  const int t = threadIdx.x;
  const int lane = t & 63, w = t >> 6;            // 16 waves
  const int t16 = t << 4;
  const float* __restrict__ X = xyz + (size_t)b * NPTS * 3;
  const float* __restrict__ ZS = szS + (size_t)b * NPTS;
  const size_t B0 = (size_t)b * NPTS;

  float z[FPS_PP], dist[FPS_PP];
  int pidp[FPS_PP / 2];
  float bxn = 1e30f, bxx = -1e30f, byn = 1e30f, byx = -1e30f, bzn = 1e30f, bzx = -1e30f;
#pragma unroll
  for (int i = 0; i < FPS_PP; ++i) {
    const float2 v = sxy2T[B0 + i * FPS_T + t];   // coalesced
    XY[i * FPS_T + t] = v;                        // conflict-free ds_write_b64
    z[i] = szT[B0 + i * FPS_T + t];               // coalesced
    dist[i] = 1e10f;
    bxn = fminf(bxn, v.x); bxx = fmaxf(bxx, v.x);
    byn = fminf(byn, v.y); byx = fmaxf(byx, v.y);
    bzn = fminf(bzn, z[i]); bzx = fmaxf(bzx, z[i]);
  }
#pragma unroll
  for (int i = 0; i < FPS_PP / 2; ++i)
    pidp[i] = siT[B0 + (2 * i) * FPS_T + t] | (siT[B0 + (2 * i + 1) * FPS_T + t] << 16);
  // wave-level bbox (uniform across the wave after butterfly)
#pragma unroll
  for (int off = 1; off < 64; off <<= 1) {
    bxn = fminf(bxn, __shfl_xor(bxn, off)); bxx = fmaxf(bxx, __shfl_xor(bxx, off));
    byn = fminf(byn, __shfl_xor(byn, off)); byx = fmaxf(byx, __shfl_xor(byx, off));
    bzn = fminf(bzn, __shfl_xor(bzn, off)); bzx = fmaxf(bzx, __shfl_xor(bzx, off));
  }
  __syncthreads();

  unsigned wkh = __float_as_uint(1e10f), wkl = 0;  // cached wave-reduced key
  int   cur = 0;
  float lx = X[0], ly = X[1], lz = X[2];

  for (int k = 0; k < NP; ++k) {
    if (t == 0) fps_idx[b * NP + k] = cur;

    // wave-uniform exact skip: d_min(center, wave bbox)^2 > mt_wave*(1+1e-5)
    // => every point's reference-order distance >= its dist => exact no-op,
    // and the cached wave key (computed from unchanged dists) stays valid.
    const float ddx = fmaxf(fmaxf(bxn - lx, lx - bxx), 0.0f);
    const float ddy = fmaxf(fmaxf(byn - ly, ly - byx), 0.0f);
    const float ddz = fmaxf(fmaxf(bzn - lz, lz - bzx), 0.0f);
    const float db2 = ddx * ddx + ddy * ddy + ddz * ddz;
    const float mtw = __uint_as_float(wkh);
    if (db2 <= mtw * 1.00001f) {                  // uniform -> s_cbranch
      float m = -1.0f;
#pragma unroll
      for (int i = 0; i < FPS_PP; ++i) {
        const float2 v = XY[i * FPS_T + t];       // ds_read_b64, conflict-free
        const float dx = v.x - lx, dy = v.y - ly, dz = z[i] - lz;
        const float d = ((dx * dx) + (dy * dy)) + (dz * dz);  // exact ref op order
        const float nd = fminf(dist[i], d);
        dist[i] = nd;
        m = fmaxf(m, nd);
      }
      unsigned sel = 0;
#pragma unroll
      for (int i = 0; i < FPS_PP; ++i) {
        const int pi = (pidp[i >> 1] >> ((i & 1) * 16)) & 0xFFFF;
        const unsigned pl = ((unsigned)(pi ^ 0x3FFF) << 14) | (unsigned)(t16 + i);
        const unsigned cand = (sel > pl) ? sel : pl;
        sel = (dist[i] == m) ? cand : sel;        // tie -> max invpid = min pid
      }
      unsigned hi = __float_as_uint(m), lo = sel;
      dpp_max64<0x111>(hi, lo);
      dpp_max64<0x112>(hi, lo);
      dpp_max64<0x114>(hi, lo);
      dpp_max64<0x118>(hi, lo);
      dpp_max64<0x142>(hi, lo);
      dpp_max64<0x143>(hi, lo);                   // lane 63 = wave max
      wkh = (unsigned)__builtin_amdgcn_readlane((int)hi, 63);
      wkl = (unsigned)__builtin_amdgcn_readlane((int)lo, 63);
    }
    const int p = k & 1;
    if (lane == 63)
      redk[p][w] = ((unsigned long long)wkh << 32) | wkl;
    __syncthreads();

    // cross-wave combine (all waves redundantly); speculative winner loads
    // (z from szS, xy from LDS) issued BEFORE the DPP combine to hide latency
    const unsigned long long kj = redk[p][lane & 15];
    const unsigned shi = (unsigned)(kj >> 32), slo = (unsigned)kj;
    const int sposj = (int)(slo & 0x3FFFu);
    const float sgz = ZS[sposj];                  // global, L2 (~200cy, overlapped)
    const float2 sxy = XY[(sposj & 15) * FPS_T + (sposj >> 4)];  // LDS (~50cy)
    unsigned h2 = shi, l2 = slo;
    dpp_max64<0x111>(h2, l2);
    dpp_max64<0x112>(h2, l2);
    dpp_max64<0x114>(h2, l2);
    dpp_max64<0x118>(h2, l2);                     // lane 15 of each row = global max
    const unsigned kmh = (unsigned)__builtin_amdgcn_readlane((int)h2, 15);
    const unsigned kml = (unsigned)__builtin_amdgcn_readlane((int)l2, 15);
    cur = (int)((kml >> 14) & 0x3FFFu) ^ 0x3FFF;  // winner original pid
    const unsigned long long tmsk = __ballot(shi == kmh && slo == kml) & 0xFFFFull;
    const int bwl = (int)__builtin_ctzll(tmsk);
    lx = __uint_as_float((unsigned)__builtin_amdgcn_readlane(__float_as_int(sxy.x), bwl));
    ly = __uint_as_float((unsigned)__builtin_amdgcn_readlane(__float_as_int(sxy.y), bwl));
    lz = __uint_as_float((unsigned)__builtin_amdgcn_readlane(__float_as_int(sgz), bwl));
    // one barrier/iter: parity double-buffer makes overwrite-while-read impossible
  }
}

// ---------------- Ball query ----------------
__global__ __launch_bounds__(256)
void ballq_kernel(const float* __restrict__ xyz, const int* __restrict__ fps_idx,
                  int* __restrict__ ball_idx)
{
#pragma clang fp contract(off)
  const int gw = (int)((blockIdx.x * blockDim.x + threadIdx.x) >> 6);
  const int lane = threadIdx.x & 63;
  const int b = gw >> 10, s = gw & 1023;
  const float* __restrict__ X = xyz + (size_t)b * NPTS * 3;
  const int ci = fps_idx[b * NP + s];
  const float cx = X[ci * 3 + 0], cy = X[ci * 3 + 1], cz = X[ci * 3 + 2];
  const float n2 = ((cx * cx) + (cy * cy)) + (cz * cz);
  int* __restrict__ out = ball_idx + (size_t)(b * NP + s) * NS;

  int cnt = 0;
  int first = -1;
  for (int c0 = 0; c0 < NPTS && cnt < NS; c0 += 64) {
    const int p = c0 + lane;
    const float x = X[p * 3 + 0], y = X[p * 3 + 1], z = X[p * 3 + 2];
    const float x2 = ((x * x) + (y * y)) + (z * z);
    const float dt = ((cx * x) + (cy * y)) + (cz * z);
    const float d2 = (n2 + x2) - (2.0f * dt);
    const bool inball = d2 < 0.04f;
    const unsigned long long mm = __ballot(inball);
    if (inball) {
      const int pos = cnt + __popcll(mm & ((1ull << lane) - 1ull));
      if (pos < NS) out[pos] = p;
    }
    if (first < 0 && mm != 0ull) first = c0 + __builtin_ctzll(mm);
    cnt += __popcll(mm);
  }
  if (cnt < NS) {
    if (first < 0) first = 0;
    if (lane >= cnt && lane < NS) out[lane] = first;
  }
}

// ---------------- Transpose feats [B][C][N] -> [B][N][C] ----------------
__global__ __launch_bounds__(256)
void transpose_kernel(const float* __restrict__ feats, float* __restrict__ featsT)
{
  __shared__ float t[32][33];
  const int b = blockIdx.z;
  const int cb = blockIdx.y * 32;
  const int nb = blockIdx.x * 32;
  const int tx = threadIdx.x;
  const int ty = threadIdx.y;
  const float* __restrict__ F = feats + (size_t)b * CIN * NPTS;
#pragma unroll
  for (int i = 0; i < 32; i += 8)
    t[ty + i][tx] = F[(size_t)(cb + ty + i) * NPTS + nb + tx];
  __syncthreads();
  float* __restrict__ FT_ = featsT + (size_t)b * NPTS * CIN;
#pragma unroll
  for (int i = 0; i < 32; i += 8)
    FT_[(size_t)(nb + ty + i) * CIN + cb + tx] = t[tx][ty + i];
}

// ---------------- Gather + max-pool ----------------
__global__ __launch_bounds__(128)
void pool_kernel(const float* __restrict__ featsT, const int* __restrict__ ball_idx,
                 float* __restrict__ pooled)
{
  const int bs = blockIdx.x;
  const int c = threadIdx.x;
  const int b = bs >> 10;
  const int* __restrict__ idx = ball_idx + (size_t)bs * NS;
  const float* __restrict__ FT_ = featsT + (size_t)b * NPTS * CIN;
  float m = -INFINITY;
#pragma unroll 4
  for (int k = 0; k < NS; ++k) {
    const int n = idx[k];
    m = fmaxf(m, FT_[(size_t)n * CIN + c]);
  }
  pooled[(size_t)bs * CIN + c] = m;
}

// ---------------- 1x1 conv + BN + LeakyReLU ----------------
#define GO 128
#define GS 64
__global__ __launch_bounds__(256, 1)
void gemm_kernel(const float* __restrict__ pooled, const float* __restrict__ W,
                 const float* __restrict__ gamma, const float* __restrict__ beta,
                 const float* __restrict__ mean, const float* __restrict__ var,
                 float* __restrict__ out)
{
  __shared__ float Wt[128 * 132];
  __shared__ float Pl[128 * 68];
  const int b = blockIdx.z;
  const int ob = blockIdx.y * GO;
  const int sb = blockIdx.x * GS;
  const int tid = threadIdx.x;

  for (int i = tid; i < GO * 128; i += 256) {
    const int o = i >> 7, c = i & 127;
    Wt[c * 132 + o] = W[(ob + o) * 128 + c];
  }
  const float* __restrict__ P = pooled + (size_t)(b * NP + sb) * 128;
  for (int i = tid; i < GS * 128; i += 256) {
    const int s = i >> 7, c = i & 127;
    Pl[c * 68 + s] = P[s * 128 + c];
  }
  __syncthreads();

  const int to = tid & 31, ts = tid >> 5;
  const int o0 = to * 4, s0 = ts * 8;
  float acc[4][8];
#pragma unroll
  for (int o = 0; o < 4; ++o)
#pragma unroll
    for (int j = 0; j < 8; ++j) acc[o][j] = 0.0f;

  for (int c = 0; c < 128; ++c) {
    const float4 wv = *(const float4*)&Wt[c * 132 + o0];
    const float4 pa = *(const float4*)&Pl[c * 68 + s0];
    const float4 pb = *(const float4*)&Pl[c * 68 + s0 + 4];
    const float wr[4] = {wv.x, wv.y, wv.z, wv.w};
    const float pr[8] = {pa.x, pa.y, pa.z, pa.w, pb.x, pb.y, pb.z, pb.w};
#pragma unroll
    for (int o = 0; o < 4; ++o)
#pragma unroll
      for (int j = 0; j < 8; ++j)
        acc[o][j] = fmaf(wr[o], pr[j], acc[o][j]);
  }

#pragma unroll
  for (int o = 0; o < 4; ++o) {
    const int oo = ob + o0 + o;
    const float sc = gamma[oo] / sqrtf(var[oo] + 1e-5f);
    const float sh = beta[oo] - mean[oo] * sc;
    float r[8];
#pragma unroll
    for (int j = 0; j < 8; ++j) {
      const float y = fmaf(acc[o][j], sc, sh);
      r[j] = (y >= 0.0f) ? y : 0.2f * y;
    }
    float* __restrict__ O = out + (size_t)(b * COUT + oo) * NP + sb + s0;
    *(float4*)&O[0] = make_float4(r[0], r[1], r[2], r[3]);
    *(float4*)&O[4] = make_float4(r[4], r[5], r[6], r[7]);
  }
}

// ---------------- launch ----------------
extern "C" void kernel_launch(void* const* d_in, const int* in_sizes, int n_in,
                              void* d_out, int out_size, void* d_ws, size_t ws_size,
                              hipStream_t stream)
{
  (void)in_sizes; (void)n_in; (void)out_size; (void)ws_size;
  const float* xyz   = (const float*)d_in[0];
  const float* feats = (const float*)d_in[1];
  const float* W     = (const float*)d_in[2];
  const float* gamma = (const float*)d_in[3];
  const float* beta  = (const float*)d_in[4];
  const float* mean  = (const float*)d_in[5];
  const float* var   = (const float*)d_in[6];
  float* out = (float*)d_out;

  char* ws = (char*)d_ws;
  // fps_idx [32KB] @0 | ball_idx [1MB] @32768 | featsT [64MB] @1081344 |
  // pooled [4MB] @68190208. Sort scratch aliases featsT head (dead before
  // transpose runs; stream order guarantees no overlap-in-time).
  int*   fps_idx  = (int*)(ws + 0);
  int*   ball_idx = (int*)(ws + 32768);
  char*  fbase    = ws + 1081344;
  float* featsT   = (float*)fbase;
  float* pooled   = (float*)(ws + 68190208);

  float2* sxy2T  = (float2*)(fbase + 0);        // 1 MB
  float*  szT    = (float*)(fbase + 1048576);   // 512 KB
  int*    siT    = (int*)(fbase + 1572864);     // 512 KB
  float*  szS    = (float*)(fbase + 2097152);   // 512 KB
  int*    hist   = (int*)(fbase + 2621440);     // 16 KB
  int*    cursor = (int*)(fbase + 2637824);     // 16 KB

  zero_hist_kernel<<<NBATCH, NCELL, 0, stream>>>(hist);
  hist_kernel<<<(NBATCH * NPTS) / 256, 256, 0, stream>>>(xyz, hist);
  scan_kernel<<<NBATCH, NCELL, 0, stream>>>(hist, cursor);
  scatter_kernel<<<(NBATCH * NPTS) / 256, 256, 0, stream>>>(xyz, cursor, sxy2T, szT, szS, siT);
  fps_kernel<<<NBATCH, FPS_T, 0, stream>>>(xyz, sxy2T, szT, szS, siT, fps_idx);
  ballq_kernel<<<(NBATCH * NP) / 4, 256, 0, stream>>>(xyz, fps_idx, ball_idx);
  transpose_kernel<<<dim3(NPTS / 32, CIN / 32, NBATCH), dim3(32, 8), 0, stream>>>(feats, featsT);
  pool_kernel<<<NBATCH * NP, CIN, 0, stream>>>(featsT, ball_idx, pooled);
  gemm_kernel<<<dim3(NP / GS, COUT / GO, NBATCH), 256, 0, stream>>>(pooled, W, gamma, beta, mean, var, out);
}